// Round 1
// baseline (2785.105 us; speedup 1.0000x reference)
//
#include <hip/hip_runtime.h>
#include <hip/hip_bf16.h>
#include <stdint.h>

#define BATCH 128
#define NTOK 245
#define HEADS 12
#define DHEAD 64
#define CDIM 768
#define NBIAS_MAX 2048

__device__ __forceinline__ float bf2f(uint32_t hbits) {
    union { uint32_t u; float f; } v; v.u = hbits << 16; return v.f;
}
__device__ __forceinline__ uint32_t f2bf(float f) {
    union { float f; uint32_t u; } v; v.f = f;
    return (v.u + 0x7fffu + ((v.u >> 16) & 1u)) >> 16;
}

// ---------------- Kernel 1: QKV projection  out[m][c] = dot(x[m], qkv_w[c]) ----------------
// M = 31360 (BM=128), N = 2304 (BN=64), K = 768 (BK=16). Exact tiling, no edges.
// Writes bf16 to ws laid out as [B][3][H][N][64].
__global__ __launch_bounds__(256)
void qkv_gemm(const float* __restrict__ x, const float* __restrict__ w,
              uint16_t* __restrict__ qkv)
{
    __shared__ float As[16][132];
    __shared__ float Ws[16][68];
    const int t  = threadIdx.x;
    const int tx = t & 15, ty = t >> 4;
    const int m0 = blockIdx.y * 128;
    const int c0 = blockIdx.x * 64;

    const int ra = t >> 1;            // A row 0..127
    const int ka = (t & 1) * 8;       // A k-offset {0,8}
    const float* aptr = x + (size_t)(m0 + ra) * CDIM + ka;
    const int rb = t >> 2;            // B row (output col) 0..63
    const int kb = (t & 3) * 4;       // {0,4,8,12}
    const float* bptr = w + (size_t)(c0 + rb) * CDIM + kb;

    float acc[8][4];
    #pragma unroll
    for (int i = 0; i < 8; ++i)
        #pragma unroll
        for (int j = 0; j < 4; ++j) acc[i][j] = 0.f;

    for (int k0 = 0; k0 < CDIM; k0 += 16) {
        float4 a0 = *(const float4*)(aptr);
        float4 a1 = *(const float4*)(aptr + 4);
        float4 b0 = *(const float4*)(bptr);
        As[ka+0][ra] = a0.x; As[ka+1][ra] = a0.y; As[ka+2][ra] = a0.z; As[ka+3][ra] = a0.w;
        As[ka+4][ra] = a1.x; As[ka+5][ra] = a1.y; As[ka+6][ra] = a1.z; As[ka+7][ra] = a1.w;
        Ws[kb+0][rb] = b0.x; Ws[kb+1][rb] = b0.y; Ws[kb+2][rb] = b0.z; Ws[kb+3][rb] = b0.w;
        __syncthreads();
        #pragma unroll
        for (int k = 0; k < 16; ++k) {
            float4 bb  = *(const float4*)&Ws[k][tx*4];
            float4 aa0 = *(const float4*)&As[k][ty*8];
            float4 aa1 = *(const float4*)&As[k][ty*8+4];
            float a[8] = {aa0.x,aa0.y,aa0.z,aa0.w,aa1.x,aa1.y,aa1.z,aa1.w};
            float b[4] = {bb.x,bb.y,bb.z,bb.w};
            #pragma unroll
            for (int i = 0; i < 8; ++i)
                #pragma unroll
                for (int j = 0; j < 4; ++j) acc[i][j] = fmaf(a[i], b[j], acc[i][j]);
        }
        __syncthreads();
        aptr += 16; bptr += 16;
    }
    // epilogue: c = c0 + tx*4 + j; within one (s,h) since 64 | c0
    const int s  = c0 / CDIM;
    const int hh = (c0 % CDIM) / DHEAD;
    const int d0 = tx * 4;
    #pragma unroll
    for (int i = 0; i < 8; ++i) {
        int m = m0 + ty*8 + i;
        int b = m / NTOK, n = m % NTOK;
        size_t base = ((((size_t)b*3 + s)*HEADS + hh)*NTOK + n)*DHEAD + d0;
        uint2 pk;
        pk.x = f2bf(acc[i][0]) | (f2bf(acc[i][1]) << 16);
        pk.y = f2bf(acc[i][2]) | (f2bf(acc[i][3]) << 16);
        *(uint2*)(qkv + base) = pk;
    }
}

// ---------------- Kernel 2: fused attention per (b,h) ----------------
// One block per (b,h); thread i (<245) owns q-row i. Online softmax in registers.
__global__ __launch_bounds__(256)
void attn_fused(const uint16_t* __restrict__ qkv, const float* __restrict__ bias_table,
                const int* __restrict__ rel, int n_bias, uint16_t* __restrict__ ows)
{
    __shared__ float bias_s[NBIAS_MAX];
    const int bh = blockIdx.x;
    const int b = bh / HEADS, h = bh % HEADS;
    const int t = threadIdx.x;
    const int nb = (n_bias < NBIAS_MAX) ? n_bias : NBIAS_MAX;
    for (int i = t; i < nb; i += 256) bias_s[i] = bias_table[(size_t)h * n_bias + i];
    __syncthreads();
    if (t >= NTOK) return;

    const uint16_t* qrow  = qkv + ((((size_t)b*3 + 0)*HEADS + h)*NTOK + t)*DHEAD;
    const uint16_t* kbase = qkv + ((((size_t)b*3 + 1)*HEADS + h)*NTOK)*DHEAD;
    const uint16_t* vbase = qkv + ((((size_t)b*3 + 2)*HEADS + h)*NTOK)*DHEAD;
    const int* relrow = rel + t * NTOK;

    float q[64], o[64];
    #pragma unroll
    for (int u = 0; u < 8; ++u) {
        uint4 r4 = *(const uint4*)(qrow + u*8);
        q[u*8+0]=bf2f(r4.x & 0xffffu); q[u*8+1]=bf2f(r4.x >> 16);
        q[u*8+2]=bf2f(r4.y & 0xffffu); q[u*8+3]=bf2f(r4.y >> 16);
        q[u*8+4]=bf2f(r4.z & 0xffffu); q[u*8+5]=bf2f(r4.z >> 16);
        q[u*8+6]=bf2f(r4.w & 0xffffu); q[u*8+7]=bf2f(r4.w >> 16);
    }
    #pragma unroll
    for (int d = 0; d < 64; ++d) o[d] = 0.f;
    float mrun = -1e30f, lrun = 0.f;

    for (int j = 0; j < NTOK; ++j) {
        const uint4* kr = (const uint4*)(kbase + (size_t)j * DHEAD);
        float s = 0.f;
        #pragma unroll
        for (int u = 0; u < 8; ++u) {
            uint4 r4 = kr[u];
            s = fmaf(q[u*8+0], bf2f(r4.x & 0xffffu), s);
            s = fmaf(q[u*8+1], bf2f(r4.x >> 16),     s);
            s = fmaf(q[u*8+2], bf2f(r4.y & 0xffffu), s);
            s = fmaf(q[u*8+3], bf2f(r4.y >> 16),     s);
            s = fmaf(q[u*8+4], bf2f(r4.z & 0xffffu), s);
            s = fmaf(q[u*8+5], bf2f(r4.z >> 16),     s);
            s = fmaf(q[u*8+6], bf2f(r4.w & 0xffffu), s);
            s = fmaf(q[u*8+7], bf2f(r4.w >> 16),     s);
        }
        s = s * 0.125f + bias_s[relrow[j]];
        float p;
        if (s > mrun) {
            float corr = __expf(mrun - s);   // first iter: exp(-huge) = 0
            lrun *= corr;
            #pragma unroll
            for (int d = 0; d < 64; ++d) o[d] *= corr;
            mrun = s;
            p = 1.f;
        } else {
            p = __expf(s - mrun);
        }
        lrun += p;
        const uint4* vr = (const uint4*)(vbase + (size_t)j * DHEAD);
        #pragma unroll
        for (int u = 0; u < 8; ++u) {
            uint4 r4 = vr[u];
            o[u*8+0] = fmaf(p, bf2f(r4.x & 0xffffu), o[u*8+0]);
            o[u*8+1] = fmaf(p, bf2f(r4.x >> 16),     o[u*8+1]);
            o[u*8+2] = fmaf(p, bf2f(r4.y & 0xffffu), o[u*8+2]);
            o[u*8+3] = fmaf(p, bf2f(r4.y >> 16),     o[u*8+3]);
            o[u*8+4] = fmaf(p, bf2f(r4.z & 0xffffu), o[u*8+4]);
            o[u*8+5] = fmaf(p, bf2f(r4.z >> 16),     o[u*8+5]);
            o[u*8+6] = fmaf(p, bf2f(r4.w & 0xffffu), o[u*8+6]);
            o[u*8+7] = fmaf(p, bf2f(r4.w >> 16),     o[u*8+7]);
        }
    }
    float inv = 1.f / lrun;
    uint16_t* orow = ows + (((size_t)b*HEADS + h)*NTOK + t)*DHEAD;
    #pragma unroll
    for (int u = 0; u < 8; ++u) {
        uint4 pk;
        pk.x = f2bf(o[u*8+0]*inv) | (f2bf(o[u*8+1]*inv) << 16);
        pk.y = f2bf(o[u*8+2]*inv) | (f2bf(o[u*8+3]*inv) << 16);
        pk.z = f2bf(o[u*8+4]*inv) | (f2bf(o[u*8+5]*inv) << 16);
        pk.w = f2bf(o[u*8+6]*inv) | (f2bf(o[u*8+7]*inv) << 16);
        *(uint4*)(orow + u*8) = pk;
    }
}

// ---------------- Kernel 3: output projection  out[m][c] = dot(O[m], proj_w[c]) + b[c] ----
// M = 31360 (BM=128), N = 768 (BN=64), K = 768 (BK=16). A from bf16 ws [B][H][N][64].
__global__ __launch_bounds__(256)
void proj_gemm(const uint16_t* __restrict__ ows, const float* __restrict__ w,
               const float* __restrict__ bias, float* __restrict__ out)
{
    __shared__ float As[16][132];
    __shared__ float Ws[16][68];
    const int t  = threadIdx.x;
    const int tx = t & 15, ty = t >> 4;
    const int m0 = blockIdx.y * 128;
    const int c0 = blockIdx.x * 64;

    const int ra = t >> 1;
    const int ka = (t & 1) * 8;
    const int ma = m0 + ra;
    const int ba = ma / NTOK, na = ma % NTOK;
    const int rb = t >> 2;
    const int kb = (t & 3) * 4;
    const float* bptr = w + (size_t)(c0 + rb) * CDIM + kb;

    float acc[8][4];
    #pragma unroll
    for (int i = 0; i < 8; ++i)
        #pragma unroll
        for (int j = 0; j < 4; ++j) acc[i][j] = 0.f;

    for (int k0 = 0; k0 < CDIM; k0 += 16) {
        const int k = k0 + ka;                       // 8 contiguous within one head block
        const uint16_t* ap = ows + (((size_t)ba*HEADS + (k >> 6))*NTOK + na)*DHEAD + (k & 63);
        uint4 r4 = *(const uint4*)ap;
        As[ka+0][ra] = bf2f(r4.x & 0xffffu); As[ka+1][ra] = bf2f(r4.x >> 16);
        As[ka+2][ra] = bf2f(r4.y & 0xffffu); As[ka+3][ra] = bf2f(r4.y >> 16);
        As[ka+4][ra] = bf2f(r4.z & 0xffffu); As[ka+5][ra] = bf2f(r4.z >> 16);
        As[ka+6][ra] = bf2f(r4.w & 0xffffu); As[ka+7][ra] = bf2f(r4.w >> 16);
        float4 b0 = *(const float4*)(bptr + k0);
        Ws[kb+0][rb] = b0.x; Ws[kb+1][rb] = b0.y; Ws[kb+2][rb] = b0.z; Ws[kb+3][rb] = b0.w;
        __syncthreads();
        #pragma unroll
        for (int k2 = 0; k2 < 16; ++k2) {
            float4 bb  = *(const float4*)&Ws[k2][tx*4];
            float4 aa0 = *(const float4*)&As[k2][ty*8];
            float4 aa1 = *(const float4*)&As[k2][ty*8+4];
            float a[8] = {aa0.x,aa0.y,aa0.z,aa0.w,aa1.x,aa1.y,aa1.z,aa1.w};
            float b[4] = {bb.x,bb.y,bb.z,bb.w};
            #pragma unroll
            for (int i = 0; i < 8; ++i)
                #pragma unroll
                for (int j = 0; j < 4; ++j) acc[i][j] = fmaf(a[i], b[j], acc[i][j]);
        }
        __syncthreads();
    }
    const int c = c0 + tx*4;
    float4 pb = *(const float4*)(bias + c);
    #pragma unroll
    for (int i = 0; i < 8; ++i) {
        int m = m0 + ty*8 + i;
        float4 r;
        r.x = acc[i][0] + pb.x;
        r.y = acc[i][1] + pb.y;
        r.z = acc[i][2] + pb.z;
        r.w = acc[i][3] + pb.w;
        *(float4*)(out + (size_t)m*CDIM + c) = r;
    }
}

extern "C" void kernel_launch(void* const* d_in, const int* in_sizes, int n_in,
                              void* d_out, int out_size, void* d_ws, size_t ws_size,
                              hipStream_t stream)
{
    (void)n_in; (void)out_size;
    const float* x          = (const float*)d_in[0];
    const float* qkv_w      = (const float*)d_in[1];
    const float* proj_w     = (const float*)d_in[2];
    const float* proj_b     = (const float*)d_in[3];
    const float* bias_table = (const float*)d_in[4];
    const int*   rel        = (const int*)d_in[5];
    const int n_bias = in_sizes[4] / HEADS;

    uint16_t* qkv_ws = (uint16_t*)d_ws;
    const size_t qkv_elems = (size_t)BATCH * 3 * HEADS * NTOK * DHEAD;  // 72,253,440
    const size_t o_elems   = (size_t)BATCH * HEADS * NTOK * DHEAD;      // 24,084,480
    uint16_t* o_ws = qkv_ws + qkv_elems;
    if (ws_size < (qkv_elems + o_elems) * sizeof(uint16_t)) return;     // ~193 MB needed

    dim3 g1(2304 / 64, 31360 / 128);   // (36, 245)
    qkv_gemm<<<g1, 256, 0, stream>>>(x, qkv_w, qkv_ws);

    attn_fused<<<dim3(BATCH * HEADS), 256, 0, stream>>>(qkv_ws, bias_table, rel, n_bias, o_ws);

    dim3 g3(768 / 64, 31360 / 128);    // (12, 245)
    proj_gemm<<<g3, 256, 0, stream>>>(o_ws, proj_w, proj_b, (float*)d_out);
}

// Round 2
// 1157.102 us; speedup vs baseline: 2.4070x; 2.4070x over previous
//
#include <hip/hip_runtime.h>
#include <hip/hip_bf16.h>
#include <stdint.h>

#define BATCH 128
#define NTOK 245
#define HEADS 12
#define DHEAD 64
#define CDIM 768
#define NBIAS_MAX 2048

typedef __attribute__((ext_vector_type(8))) short short8;
typedef __attribute__((ext_vector_type(4))) float f32x4;

__device__ __forceinline__ float bf2f(uint32_t hbits) {
    union { uint32_t u; float f; } v; v.u = hbits << 16; return v.f;
}
__device__ __forceinline__ uint32_t f2bf(float f) {
    union { float f; uint32_t u; } v; v.f = f;
    return (v.u + 0x7fffu + ((v.u >> 16) & 1u)) >> 16;
}
__device__ __forceinline__ ushort2 pk2bf(float x, float y) {
    union { __hip_bfloat162 h; ushort2 u; } c;
    c.h = __float22bfloat162_rn(make_float2(x, y));
    return c.u;
}

// =============== Kernel 1: QKV projection, bf16 MFMA =======================
// C[m][c] = dot(x[m][:], qkv_w[c][:]) ; M=31360, N=2304, K=768.
// 128x128 tile, BK=32, 4 waves (each owns 64x64), mfma_f32_16x16x32_bf16.
// Output scattered to qkv_ws[b][s][h][tok][d] as bf16.
__global__ __launch_bounds__(256)
void qkv_gemm_mfma(const float* __restrict__ A, const float* __restrict__ Bw,
                   uint16_t* __restrict__ qkv)
{
    __shared__ ushort As[128][40];   // row stride 80B = 5*16B (aligned b128, ~2-way banks)
    __shared__ ushort Bs[128][40];
    const int t  = threadIdx.x;
    const int w  = t >> 6, l = t & 63;
    const int wr = w >> 1, wc = w & 1;
    const int lm = l & 15, lk = l >> 4;        // frag row/col sel, k-group
    const int m0 = blockIdx.y * 128, c0 = blockIdx.x * 128;

    // staging: 4 rounds of (row = t>>3 + i*32, 4 fp32 at col (t&7)*4)
    const int sr = t >> 3;          // 0..31
    const int sc = (t & 7) * 4;     // 0..28
    const float* aptr = A  + (size_t)(m0 + sr) * CDIM + sc;
    const float* bptr = Bw + (size_t)(c0 + sr) * CDIM + sc;
    const size_t rstep = (size_t)32 * CDIM;

    f32x4 acc[4][4];
    #pragma unroll
    for (int m = 0; m < 4; ++m)
        #pragma unroll
        for (int n = 0; n < 4; ++n) acc[m][n] = 0.f;

    float4 ra[4], rb[4];
    #pragma unroll
    for (int i = 0; i < 4; ++i) {
        ra[i] = *(const float4*)(aptr + i * rstep);
        rb[i] = *(const float4*)(bptr + i * rstep);
    }

    for (int kt = 0; kt < CDIM / 32; ++kt) {
        #pragma unroll
        for (int i = 0; i < 4; ++i) {
            ushort4 pa, pb;
            ushort2 p0 = pk2bf(ra[i].x, ra[i].y), p1 = pk2bf(ra[i].z, ra[i].w);
            pa.x = p0.x; pa.y = p0.y; pa.z = p1.x; pa.w = p1.y;
            p0 = pk2bf(rb[i].x, rb[i].y); p1 = pk2bf(rb[i].z, rb[i].w);
            pb.x = p0.x; pb.y = p0.y; pb.z = p1.x; pb.w = p1.y;
            *(ushort4*)&As[sr + i*32][sc] = pa;
            *(ushort4*)&Bs[sr + i*32][sc] = pb;
        }
        __syncthreads();
        if (kt < CDIM / 32 - 1) {
            const int ko = (kt + 1) * 32;
            #pragma unroll
            for (int i = 0; i < 4; ++i) {
                ra[i] = *(const float4*)(aptr + ko + i * rstep);
                rb[i] = *(const float4*)(bptr + ko + i * rstep);
            }
        }
        short8 af[4], bf[4];
        #pragma unroll
        for (int m = 0; m < 4; ++m)
            af[m] = *(const short8*)&As[wr*64 + m*16 + lm][lk * 8];
        #pragma unroll
        for (int n = 0; n < 4; ++n)
            bf[n] = *(const short8*)&Bs[wc*64 + n*16 + lm][lk * 8];
        #pragma unroll
        for (int m = 0; m < 4; ++m)
            #pragma unroll
            for (int n = 0; n < 4; ++n)
                acc[m][n] = __builtin_amdgcn_mfma_f32_16x16x32_bf16(af[m], bf[n], acc[m][n], 0, 0, 0);
        __syncthreads();
    }

    // epilogue: C[row][col] -> qkv_ws[b][s][h][tok][d]
    int sarr[4], harr[4], darr[4];
    #pragma unroll
    for (int n = 0; n < 4; ++n) {
        int c = c0 + wc*64 + n*16 + lm;
        int s = c / CDIM; int rem = c - s * CDIM;
        sarr[n] = s; harr[n] = rem >> 6; darr[n] = rem & 63;
    }
    #pragma unroll
    for (int m = 0; m < 4; ++m) {
        #pragma unroll
        for (int r = 0; r < 4; ++r) {
            int gm  = m0 + wr*64 + m*16 + lk*4 + r;
            int b   = gm / NTOK;
            int tok = gm - b * NTOK;
            #pragma unroll
            for (int n = 0; n < 4; ++n) {
                size_t addr = ((((size_t)b*3 + sarr[n])*HEADS + harr[n])*NTOK + tok)*DHEAD + darr[n];
                qkv[addr] = (uint16_t)f2bf(acc[m][n][r]);
            }
        }
    }
}

// =============== Kernel 2: fused attention per (b,h) (unchanged) ===========
__global__ __launch_bounds__(256)
void attn_fused(const uint16_t* __restrict__ qkv, const float* __restrict__ bias_table,
                const int* __restrict__ rel, int n_bias, uint16_t* __restrict__ ows)
{
    __shared__ float bias_s[NBIAS_MAX];
    const int bh = blockIdx.x;
    const int b = bh / HEADS, h = bh % HEADS;
    const int t = threadIdx.x;
    const int nb = (n_bias < NBIAS_MAX) ? n_bias : NBIAS_MAX;
    for (int i = t; i < nb; i += 256) bias_s[i] = bias_table[(size_t)h * n_bias + i];
    __syncthreads();
    if (t >= NTOK) return;

    const uint16_t* qrow  = qkv + ((((size_t)b*3 + 0)*HEADS + h)*NTOK + t)*DHEAD;
    const uint16_t* kbase = qkv + ((((size_t)b*3 + 1)*HEADS + h)*NTOK)*DHEAD;
    const uint16_t* vbase = qkv + ((((size_t)b*3 + 2)*HEADS + h)*NTOK)*DHEAD;
    const int* relrow = rel + t * NTOK;

    float q[64], o[64];
    #pragma unroll
    for (int u = 0; u < 8; ++u) {
        uint4 r4 = *(const uint4*)(qrow + u*8);
        q[u*8+0]=bf2f(r4.x & 0xffffu); q[u*8+1]=bf2f(r4.x >> 16);
        q[u*8+2]=bf2f(r4.y & 0xffffu); q[u*8+3]=bf2f(r4.y >> 16);
        q[u*8+4]=bf2f(r4.z & 0xffffu); q[u*8+5]=bf2f(r4.z >> 16);
        q[u*8+6]=bf2f(r4.w & 0xffffu); q[u*8+7]=bf2f(r4.w >> 16);
    }
    #pragma unroll
    for (int d = 0; d < 64; ++d) o[d] = 0.f;
    float mrun = -1e30f, lrun = 0.f;

    for (int j = 0; j < NTOK; ++j) {
        const uint4* kr = (const uint4*)(kbase + (size_t)j * DHEAD);
        float s = 0.f;
        #pragma unroll
        for (int u = 0; u < 8; ++u) {
            uint4 r4 = kr[u];
            s = fmaf(q[u*8+0], bf2f(r4.x & 0xffffu), s);
            s = fmaf(q[u*8+1], bf2f(r4.x >> 16),     s);
            s = fmaf(q[u*8+2], bf2f(r4.y & 0xffffu), s);
            s = fmaf(q[u*8+3], bf2f(r4.y >> 16),     s);
            s = fmaf(q[u*8+4], bf2f(r4.z & 0xffffu), s);
            s = fmaf(q[u*8+5], bf2f(r4.z >> 16),     s);
            s = fmaf(q[u*8+6], bf2f(r4.w & 0xffffu), s);
            s = fmaf(q[u*8+7], bf2f(r4.w >> 16),     s);
        }
        s = s * 0.125f + bias_s[relrow[j]];
        float p;
        if (s > mrun) {
            float corr = __expf(mrun - s);
            lrun *= corr;
            #pragma unroll
            for (int d = 0; d < 64; ++d) o[d] *= corr;
            mrun = s;
            p = 1.f;
        } else {
            p = __expf(s - mrun);
        }
        lrun += p;
        const uint4* vr = (const uint4*)(vbase + (size_t)j * DHEAD);
        #pragma unroll
        for (int u = 0; u < 8; ++u) {
            uint4 r4 = vr[u];
            o[u*8+0] = fmaf(p, bf2f(r4.x & 0xffffu), o[u*8+0]);
            o[u*8+1] = fmaf(p, bf2f(r4.x >> 16),     o[u*8+1]);
            o[u*8+2] = fmaf(p, bf2f(r4.y & 0xffffu), o[u*8+2]);
            o[u*8+3] = fmaf(p, bf2f(r4.y >> 16),     o[u*8+3]);
            o[u*8+4] = fmaf(p, bf2f(r4.z & 0xffffu), o[u*8+4]);
            o[u*8+5] = fmaf(p, bf2f(r4.z >> 16),     o[u*8+5]);
            o[u*8+6] = fmaf(p, bf2f(r4.w & 0xffffu), o[u*8+6]);
            o[u*8+7] = fmaf(p, bf2f(r4.w >> 16),     o[u*8+7]);
        }
    }
    float inv = 1.f / lrun;
    uint16_t* orow = ows + (((size_t)b*HEADS + h)*NTOK + t)*DHEAD;
    #pragma unroll
    for (int u = 0; u < 8; ++u) {
        uint4 pk;
        pk.x = f2bf(o[u*8+0]*inv) | (f2bf(o[u*8+1]*inv) << 16);
        pk.y = f2bf(o[u*8+2]*inv) | (f2bf(o[u*8+3]*inv) << 16);
        pk.z = f2bf(o[u*8+4]*inv) | (f2bf(o[u*8+5]*inv) << 16);
        pk.w = f2bf(o[u*8+6]*inv) | (f2bf(o[u*8+7]*inv) << 16);
        *(uint4*)(orow + u*8) = pk;
    }
}

// =============== Kernel 3: output projection, bf16 MFMA ====================
// C[m][c] = dot(O[m][:], proj_w[c][:]) + bias[c]; M=31360, N=768, K=768.
// A from bf16 ows[b][h][tok][d] (k = h*64+d), B=proj_w fp32.
__global__ __launch_bounds__(256)
void proj_gemm_mfma(const uint16_t* __restrict__ ows, const float* __restrict__ Bw,
                    const float* __restrict__ bias, float* __restrict__ out)
{
    __shared__ ushort As[128][40];
    __shared__ ushort Bs[128][40];
    const int t  = threadIdx.x;
    const int w  = t >> 6, l = t & 63;
    const int wr = w >> 1, wc = w & 1;
    const int lm = l & 15, lk = l >> 4;
    const int m0 = blockIdx.y * 128, c0 = blockIdx.x * 128;

    // A staging: 2 rounds of 16B bf16 loads. row = t>>2 + i*64, col8 = (t&3)*8
    const int sr2 = t >> 2;          // 0..63
    const int sc2 = (t & 3) * 8;     // 0,8,16,24
    size_t abase[2];
    #pragma unroll
    for (int i = 0; i < 2; ++i) {
        int gm  = m0 + sr2 + i*64;
        int b   = gm / NTOK;
        int tok = gm - b * NTOK;
        abase[i] = ((size_t)b * HEADS * NTOK + tok) * DHEAD + sc2;   // + h*NTOK*64 + (kt&1)*32
    }
    // B staging: 4 rounds of 4 fp32. row = t>>3 + i*32, col4 = (t&7)*4
    const int sr = t >> 3, sc = (t & 7) * 4;
    const float* bptr = Bw + (size_t)(c0 + sr) * CDIM + sc;
    const size_t rstep = (size_t)32 * CDIM;

    f32x4 acc[4][4];
    #pragma unroll
    for (int m = 0; m < 4; ++m)
        #pragma unroll
        for (int n = 0; n < 4; ++n) acc[m][n] = 0.f;

    uint4  pa[2];
    float4 pb[4];
    #pragma unroll
    for (int i = 0; i < 2; ++i)
        pa[i] = *(const uint4*)(ows + abase[i]);      // kt=0: h=0, off 0
    #pragma unroll
    for (int i = 0; i < 4; ++i)
        pb[i] = *(const float4*)(bptr + i * rstep);

    for (int kt = 0; kt < CDIM / 32; ++kt) {
        #pragma unroll
        for (int i = 0; i < 2; ++i)
            *(uint4*)&As[sr2 + i*64][sc2] = pa[i];
        #pragma unroll
        for (int i = 0; i < 4; ++i) {
            ushort4 pkv;
            ushort2 p0 = pk2bf(pb[i].x, pb[i].y), p1 = pk2bf(pb[i].z, pb[i].w);
            pkv.x = p0.x; pkv.y = p0.y; pkv.z = p1.x; pkv.w = p1.y;
            *(ushort4*)&Bs[sr + i*32][sc] = pkv;
        }
        __syncthreads();
        if (kt < CDIM / 32 - 1) {
            const int kn = kt + 1;
            const size_t aoff = (size_t)(kn >> 1) * NTOK * DHEAD + (kn & 1) * 32;
            #pragma unroll
            for (int i = 0; i < 2; ++i)
                pa[i] = *(const uint4*)(ows + abase[i] + aoff);
            #pragma unroll
            for (int i = 0; i < 4; ++i)
                pb[i] = *(const float4*)(bptr + kn * 32 + i * rstep);
        }
        short8 af[4], bf[4];
        #pragma unroll
        for (int m = 0; m < 4; ++m)
            af[m] = *(const short8*)&As[wr*64 + m*16 + lm][lk * 8];
        #pragma unroll
        for (int n = 0; n < 4; ++n)
            bf[n] = *(const short8*)&Bs[wc*64 + n*16 + lm][lk * 8];
        #pragma unroll
        for (int m = 0; m < 4; ++m)
            #pragma unroll
            for (int n = 0; n < 4; ++n)
                acc[m][n] = __builtin_amdgcn_mfma_f32_16x16x32_bf16(af[m], bf[n], acc[m][n], 0, 0, 0);
        __syncthreads();
    }

    float bs[4]; int carr[4];
    #pragma unroll
    for (int n = 0; n < 4; ++n) {
        carr[n] = c0 + wc*64 + n*16 + lm;
        bs[n]   = bias[carr[n]];
    }
    #pragma unroll
    for (int m = 0; m < 4; ++m) {
        #pragma unroll
        for (int r = 0; r < 4; ++r) {
            int gm = m0 + wr*64 + m*16 + lk*4 + r;
            #pragma unroll
            for (int n = 0; n < 4; ++n)
                out[(size_t)gm * CDIM + carr[n]] = acc[m][n][r] + bs[n];
        }
    }
}

extern "C" void kernel_launch(void* const* d_in, const int* in_sizes, int n_in,
                              void* d_out, int out_size, void* d_ws, size_t ws_size,
                              hipStream_t stream)
{
    (void)n_in; (void)out_size;
    const float* x          = (const float*)d_in[0];
    const float* qkv_w      = (const float*)d_in[1];
    const float* proj_w     = (const float*)d_in[2];
    const float* proj_b     = (const float*)d_in[3];
    const float* bias_table = (const float*)d_in[4];
    const int*   rel        = (const int*)d_in[5];
    const int n_bias = in_sizes[4] / HEADS;

    uint16_t* qkv_ws = (uint16_t*)d_ws;
    const size_t qkv_elems = (size_t)BATCH * 3 * HEADS * NTOK * DHEAD;
    const size_t o_elems   = (size_t)BATCH * HEADS * NTOK * DHEAD;
    uint16_t* o_ws = qkv_ws + qkv_elems;
    if (ws_size < (qkv_elems + o_elems) * sizeof(uint16_t)) return;

    dim3 g1(2304 / 128, 31360 / 128);   // (18, 245)
    qkv_gemm_mfma<<<g1, 256, 0, stream>>>(x, qkv_w, qkv_ws);

    attn_fused<<<dim3(BATCH * HEADS), 256, 0, stream>>>(qkv_ws, bias_table, rel, n_bias, o_ws);

    dim3 g3(768 / 128, 31360 / 128);    // (6, 245)
    proj_gemm_mfma<<<g3, 256, 0, stream>>>(o_ws, proj_w, proj_b, (float*)d_out);
}

// Round 3
// 563.816 us; speedup vs baseline: 4.9397x; 2.0523x over previous
//
#include <hip/hip_runtime.h>
#include <hip/hip_bf16.h>
#include <stdint.h>

#define BATCH 128
#define NTOK 245
#define HEADS 12
#define DHEAD 64
#define CDIM 768

typedef __attribute__((ext_vector_type(8))) short short8;
typedef __attribute__((ext_vector_type(4))) float f32x4;

__device__ __forceinline__ float bf2f(uint32_t hbits) {
    union { uint32_t u; float f; } v; v.u = hbits << 16; return v.f;
}
__device__ __forceinline__ uint32_t f2bf(float f) {
    union { float f; uint32_t u; } v; v.f = f;
    return (v.u + 0x7fffu + ((v.u >> 16) & 1u)) >> 16;
}
__device__ __forceinline__ ushort2 pk2bf(float x, float y) {
    union { __hip_bfloat162 h; ushort2 u; } c;
    c.h = __float22bfloat162_rn(make_float2(x, y));
    return c.u;
}

// =============== Kernel 0: bias precompute =================================
// bias_t[h][j][q] = bias_table[h][rel[q][j]] (bf16), pads = -30000 (mask).
__global__ __launch_bounds__(256)
void bias_pre(const float* __restrict__ bias_table, const int* __restrict__ rel,
              int n_bias, uint16_t* __restrict__ bias_t)
{
    const int h = blockIdx.x, j = blockIdx.y, q = threadIdx.x;
    float v = -30000.f;
    if (j < NTOK && q < NTOK) v = bias_table[(size_t)h * n_bias + rel[q * NTOK + j]];
    bias_t[((size_t)h * 256 + j) * 256 + q] = (uint16_t)f2bf(v);
}

// =============== Kernel 1: QKV projection, bf16 MFMA =======================
// Q,K -> qk_ws[b][s][h][tok][64]; V -> v_ws[b][h][d][256] (transposed).
__global__ __launch_bounds__(256)
void qkv_gemm_mfma(const float* __restrict__ A, const float* __restrict__ Bw,
                   uint16_t* __restrict__ qk_ws, uint16_t* __restrict__ v_ws)
{
    __shared__ ushort As[128][40];
    __shared__ ushort Bs[128][40];
    const int t  = threadIdx.x;
    const int w  = t >> 6, l = t & 63;
    const int wr = w >> 1, wc = w & 1;
    const int lm = l & 15, lk = l >> 4;
    const int m0 = blockIdx.y * 128, c0 = blockIdx.x * 128;

    const int sr = t >> 3;
    const int sc = (t & 7) * 4;
    const float* aptr = A  + (size_t)(m0 + sr) * CDIM + sc;
    const float* bptr = Bw + (size_t)(c0 + sr) * CDIM + sc;
    const size_t rstep = (size_t)32 * CDIM;

    f32x4 acc[4][4];
    #pragma unroll
    for (int m = 0; m < 4; ++m)
        #pragma unroll
        for (int n = 0; n < 4; ++n) acc[m][n] = (f32x4){0.f,0.f,0.f,0.f};

    float4 ra[4], rb[4];
    #pragma unroll
    for (int i = 0; i < 4; ++i) {
        ra[i] = *(const float4*)(aptr + i * rstep);
        rb[i] = *(const float4*)(bptr + i * rstep);
    }

    for (int kt = 0; kt < CDIM / 32; ++kt) {
        #pragma unroll
        for (int i = 0; i < 4; ++i) {
            ushort4 pa, pb;
            ushort2 p0 = pk2bf(ra[i].x, ra[i].y), p1 = pk2bf(ra[i].z, ra[i].w);
            pa.x = p0.x; pa.y = p0.y; pa.z = p1.x; pa.w = p1.y;
            p0 = pk2bf(rb[i].x, rb[i].y); p1 = pk2bf(rb[i].z, rb[i].w);
            pb.x = p0.x; pb.y = p0.y; pb.z = p1.x; pb.w = p1.y;
            *(ushort4*)&As[sr + i*32][sc] = pa;
            *(ushort4*)&Bs[sr + i*32][sc] = pb;
        }
        __syncthreads();
        if (kt < CDIM / 32 - 1) {
            const int ko = (kt + 1) * 32;
            #pragma unroll
            for (int i = 0; i < 4; ++i) {
                ra[i] = *(const float4*)(aptr + ko + i * rstep);
                rb[i] = *(const float4*)(bptr + ko + i * rstep);
            }
        }
        short8 af[4], bf[4];
        #pragma unroll
        for (int m = 0; m < 4; ++m)
            af[m] = *(const short8*)&As[wr*64 + m*16 + lm][lk * 8];
        #pragma unroll
        for (int n = 0; n < 4; ++n)
            bf[n] = *(const short8*)&Bs[wc*64 + n*16 + lm][lk * 8];
        #pragma unroll
        for (int m = 0; m < 4; ++m)
            #pragma unroll
            for (int n = 0; n < 4; ++n)
                acc[m][n] = __builtin_amdgcn_mfma_f32_16x16x32_bf16(af[m], bf[n], acc[m][n], 0, 0, 0);
        __syncthreads();
    }

    int sarr[4], harr[4], darr[4];
    #pragma unroll
    for (int n = 0; n < 4; ++n) {
        int c = c0 + wc*64 + n*16 + lm;
        int s = c / CDIM; int rem = c - s * CDIM;
        sarr[n] = s; harr[n] = rem >> 6; darr[n] = rem & 63;
    }
    #pragma unroll
    for (int m = 0; m < 4; ++m) {
        #pragma unroll
        for (int r = 0; r < 4; ++r) {
            int gm  = m0 + wr*64 + m*16 + lk*4 + r;
            int b   = gm / NTOK;
            int tok = gm - b * NTOK;
            #pragma unroll
            for (int n = 0; n < 4; ++n) {
                uint16_t val = (uint16_t)f2bf(acc[m][n][r]);
                if (sarr[n] == 2) {
                    v_ws[(((size_t)b*HEADS + harr[n])*DHEAD + darr[n])*256 + tok] = val;
                } else {
                    qk_ws[((((size_t)b*2 + sarr[n])*HEADS + harr[n])*NTOK + tok)*DHEAD + darr[n]] = val;
                }
            }
        }
    }
}

// =============== Kernel 2: MFMA flash attention per (b,h) ==================
// 8 waves x 32 q-rows. K,Vt staged in LDS once; 4 j-blocks of 64, online softmax.
__global__ __launch_bounds__(512)
void attn_mfma(const uint16_t* __restrict__ qk, const uint16_t* __restrict__ vt,
               const uint16_t* __restrict__ bias_t, uint16_t* __restrict__ ows)
{
    __shared__ ushort Ks[256][72];    // 36864 B
    __shared__ ushort Vt[64][264];    // 33792 B
    __shared__ ushort Ps[8][16][72];  // 18432 B
    const int bh = blockIdx.x;
    const int b = bh / HEADS, h = bh % HEADS;
    const int t = threadIdx.x;
    const int w = t >> 6, l = t & 63;
    const int lm = l & 15, lk = l >> 4;
    const int wq0 = w * 32;

    const uint16_t* qbase = qk + (((size_t)b*2 + 0)*HEADS + h) * (NTOK*DHEAD);
    const uint16_t* kbase = qk + (((size_t)b*2 + 1)*HEADS + h) * (NTOK*DHEAD);
    const uint16_t* vbase = vt + ((size_t)b*HEADS + h) * (DHEAD*256);
    const uint16_t* btab  = bias_t + (size_t)h * 256 * 256;

    // ---- stage K (rows >= 245 zeroed) ----
    {
        const int col = (t & 7) * 8;
        #pragma unroll
        for (int p = 0; p < 4; ++p) {
            int row = p * 64 + (t >> 3);
            uint4 val = make_uint4(0u,0u,0u,0u);
            if (row < NTOK) val = *(const uint4*)(kbase + (size_t)row * DHEAD + col);
            *(uint4*)&Ks[row][col] = val;
        }
    }
    // ---- stage Vt (cols >= 245 zeroed in-register) ----
    {
        const int col = (t & 15) * 16;
        #pragma unroll
        for (int p = 0; p < 2; ++p) {
            int row = p * 32 + (t >> 4);
            const uint16_t* src = vbase + (size_t)row * 256;
            uint4 v0 = *(const uint4*)(src + col);
            uint4 v1 = *(const uint4*)(src + col + 8);
            if (col == 240) { v0.z &= 0xffffu; v0.w = 0u; v1 = make_uint4(0u,0u,0u,0u); }
            *(uint4*)&Vt[row][col]     = v0;
            *(uint4*)&Vt[row][col + 8] = v1;
        }
    }

    // ---- Q fragments (rows clamped to 244; clamped rows never stored) ----
    short8 qf[2][2];
    #pragma unroll
    for (int m = 0; m < 2; ++m) {
        int qrow = wq0 + m*16 + lm; if (qrow > NTOK-1) qrow = NTOK-1;
        #pragma unroll
        for (int k2 = 0; k2 < 2; ++k2)
            qf[m][k2] = *(const short8*)(qbase + (size_t)qrow * DHEAD + k2*32 + lk*8);
    }

    f32x4 acc_o[2][4];
    float mrun[2][4], lrun[2][4];
    #pragma unroll
    for (int m = 0; m < 2; ++m) {
        #pragma unroll
        for (int n = 0; n < 4; ++n) acc_o[m][n] = (f32x4){0.f,0.f,0.f,0.f};
        #pragma unroll
        for (int r = 0; r < 4; ++r) { mrun[m][r] = -1e30f; lrun[m][r] = 0.f; }
    }

    __syncthreads();

    for (int jb = 0; jb < 4; ++jb) {
        short8 kf[4][2], vf[4][2];
        #pragma unroll
        for (int n = 0; n < 4; ++n)
            #pragma unroll
            for (int k2 = 0; k2 < 2; ++k2) {
                kf[n][k2] = *(const short8*)&Ks[jb*64 + n*16 + lm][k2*32 + lk*8];
                vf[n][k2] = *(const short8*)&Vt[n*16 + lm][jb*64 + k2*32 + lk*8];
            }

        #pragma unroll
        for (int m = 0; m < 2; ++m) {
            // S = Q K^T (64 x 64 for this m-tile row-block)
            f32x4 sv[4];
            #pragma unroll
            for (int n = 0; n < 4; ++n) {
                f32x4 z = (f32x4){0.f,0.f,0.f,0.f};
                sv[n] = __builtin_amdgcn_mfma_f32_16x16x32_bf16(qf[m][0], kf[n][0], z, 0, 0, 0);
                sv[n] = __builtin_amdgcn_mfma_f32_16x16x32_bf16(qf[m][1], kf[n][1], sv[n], 0, 0, 0);
            }
            // scale + bias (bias_t[h][j][q], 4 contiguous q per lane)
            #pragma unroll
            for (int n = 0; n < 4; ++n) {
                uint2 bb = *(const uint2*)(btab + (size_t)(jb*64 + n*16 + lm) * 256 + wq0 + m*16 + lk*4);
                sv[n][0] = fmaf(sv[n][0], 0.125f, bf2f(bb.x & 0xffffu));
                sv[n][1] = fmaf(sv[n][1], 0.125f, bf2f(bb.x >> 16));
                sv[n][2] = fmaf(sv[n][2], 0.125f, bf2f(bb.y & 0xffffu));
                sv[n][3] = fmaf(sv[n][3], 0.125f, bf2f(bb.y >> 16));
            }
            // online softmax: rows are (lk*4+r), spread over 16 lm lanes x 4 n
            float nm[4], corr[4];
            #pragma unroll
            for (int r = 0; r < 4; ++r) {
                float rmax = fmaxf(fmaxf(sv[0][r], sv[1][r]), fmaxf(sv[2][r], sv[3][r]));
                rmax = fmaxf(rmax, __shfl_xor(rmax, 1));
                rmax = fmaxf(rmax, __shfl_xor(rmax, 2));
                rmax = fmaxf(rmax, __shfl_xor(rmax, 4));
                rmax = fmaxf(rmax, __shfl_xor(rmax, 8));
                nm[r] = fmaxf(mrun[m][r], rmax);
                corr[r] = __expf(mrun[m][r] - nm[r]);
                mrun[m][r] = nm[r];
            }
            ushort pu[4][4];
            float rs[4] = {0.f, 0.f, 0.f, 0.f};
            #pragma unroll
            for (int n = 0; n < 4; ++n)
                #pragma unroll
                for (int r = 0; r < 4; ++r) {
                    float p = __expf(sv[n][r] - nm[r]);
                    ushort u = (ushort)f2bf(p);
                    pu[n][r] = u;
                    rs[r] += bf2f(u);   // denominator from ROUNDED p (consistency)
                }
            #pragma unroll
            for (int r = 0; r < 4; ++r) {
                rs[r] += __shfl_xor(rs[r], 1);
                rs[r] += __shfl_xor(rs[r], 2);
                rs[r] += __shfl_xor(rs[r], 4);
                rs[r] += __shfl_xor(rs[r], 8);
                lrun[m][r] = lrun[m][r] * corr[r] + rs[r];
            }
            #pragma unroll
            for (int n = 0; n < 4; ++n)
                #pragma unroll
                for (int r = 0; r < 4; ++r)
                    acc_o[m][n][r] *= corr[r];
            // P -> LDS -> A-frags
            #pragma unroll
            for (int n = 0; n < 4; ++n)
                #pragma unroll
                for (int r = 0; r < 4; ++r)
                    Ps[w][lk*4 + r][n*16 + lm] = pu[n][r];
            short8 pf[2];
            #pragma unroll
            for (int k2 = 0; k2 < 2; ++k2)
                pf[k2] = *(const short8*)&Ps[w][lm][k2*32 + lk*8];
            #pragma unroll
            for (int n = 0; n < 4; ++n) {
                acc_o[m][n] = __builtin_amdgcn_mfma_f32_16x16x32_bf16(pf[0], vf[n][0], acc_o[m][n], 0, 0, 0);
                acc_o[m][n] = __builtin_amdgcn_mfma_f32_16x16x32_bf16(pf[1], vf[n][1], acc_o[m][n], 0, 0, 0);
            }
        }
    }

    // ---- epilogue: O /= l, store bf16 to ows[b][h][q][d] ----
    uint16_t* obase = ows + ((size_t)b*HEADS + h) * (NTOK*DHEAD);
    #pragma unroll
    for (int m = 0; m < 2; ++m) {
        float inv[4];
        #pragma unroll
        for (int r = 0; r < 4; ++r) inv[r] = 1.f / lrun[m][r];
        #pragma unroll
        for (int r = 0; r < 4; ++r) {
            int q = wq0 + m*16 + lk*4 + r;
            if (q < NTOK) {
                #pragma unroll
                for (int n = 0; n < 4; ++n)
                    obase[(size_t)q * DHEAD + n*16 + lm] = (uint16_t)f2bf(acc_o[m][n][r] * inv[r]);
            }
        }
    }
}

// =============== Kernel 3: output projection, bf16 MFMA ====================
__global__ __launch_bounds__(256)
void proj_gemm_mfma(const uint16_t* __restrict__ ows, const float* __restrict__ Bw,
                    const float* __restrict__ bias, float* __restrict__ out)
{
    __shared__ ushort As[128][40];
    __shared__ ushort Bs[128][40];
    const int t  = threadIdx.x;
    const int w  = t >> 6, l = t & 63;
    const int wr = w >> 1, wc = w & 1;
    const int lm = l & 15, lk = l >> 4;
    const int m0 = blockIdx.y * 128, c0 = blockIdx.x * 128;

    const int sr2 = t >> 2;
    const int sc2 = (t & 3) * 8;
    size_t abase[2];
    #pragma unroll
    for (int i = 0; i < 2; ++i) {
        int gm  = m0 + sr2 + i*64;
        int b   = gm / NTOK;
        int tok = gm - b * NTOK;
        abase[i] = ((size_t)b * HEADS * NTOK + tok) * DHEAD + sc2;
    }
    const int sr = t >> 3, sc = (t & 7) * 4;
    const float* bptr = Bw + (size_t)(c0 + sr) * CDIM + sc;
    const size_t rstep = (size_t)32 * CDIM;

    f32x4 acc[4][4];
    #pragma unroll
    for (int m = 0; m < 4; ++m)
        #pragma unroll
        for (int n = 0; n < 4; ++n) acc[m][n] = (f32x4){0.f,0.f,0.f,0.f};

    uint4  pa[2];
    float4 pb[4];
    #pragma unroll
    for (int i = 0; i < 2; ++i)
        pa[i] = *(const uint4*)(ows + abase[i]);
    #pragma unroll
    for (int i = 0; i < 4; ++i)
        pb[i] = *(const float4*)(bptr + i * rstep);

    for (int kt = 0; kt < CDIM / 32; ++kt) {
        #pragma unroll
        for (int i = 0; i < 2; ++i)
            *(uint4*)&As[sr2 + i*64][sc2] = pa[i];
        #pragma unroll
        for (int i = 0; i < 4; ++i) {
            ushort4 pkv;
            ushort2 p0 = pk2bf(pb[i].x, pb[i].y), p1 = pk2bf(pb[i].z, pb[i].w);
            pkv.x = p0.x; pkv.y = p0.y; pkv.z = p1.x; pkv.w = p1.y;
            *(ushort4*)&Bs[sr + i*32][sc] = pkv;
        }
        __syncthreads();
        if (kt < CDIM / 32 - 1) {
            const int kn = kt + 1;
            const size_t aoff = (size_t)(kn >> 1) * NTOK * DHEAD + (kn & 1) * 32;
            #pragma unroll
            for (int i = 0; i < 2; ++i)
                pa[i] = *(const uint4*)(ows + abase[i] + aoff);
            #pragma unroll
            for (int i = 0; i < 4; ++i)
                pb[i] = *(const float4*)(bptr + kn * 32 + i * rstep);
        }
        short8 af[4], bf[4];
        #pragma unroll
        for (int m = 0; m < 4; ++m)
            af[m] = *(const short8*)&As[wr*64 + m*16 + lm][lk * 8];
        #pragma unroll
        for (int n = 0; n < 4; ++n)
            bf[n] = *(const short8*)&Bs[wc*64 + n*16 + lm][lk * 8];
        #pragma unroll
        for (int m = 0; m < 4; ++m)
            #pragma unroll
            for (int n = 0; n < 4; ++n)
                acc[m][n] = __builtin_amdgcn_mfma_f32_16x16x32_bf16(af[m], bf[n], acc[m][n], 0, 0, 0);
        __syncthreads();
    }

    float bs[4]; int carr[4];
    #pragma unroll
    for (int n = 0; n < 4; ++n) {
        carr[n] = c0 + wc*64 + n*16 + lm;
        bs[n]   = bias[carr[n]];
    }
    #pragma unroll
    for (int m = 0; m < 4; ++m) {
        #pragma unroll
        for (int r = 0; r < 4; ++r) {
            int gm = m0 + wr*64 + m*16 + lk*4 + r;
            #pragma unroll
            for (int n = 0; n < 4; ++n)
                out[(size_t)gm * CDIM + carr[n]] = acc[m][n][r] + bs[n];
        }
    }
}

extern "C" void kernel_launch(void* const* d_in, const int* in_sizes, int n_in,
                              void* d_out, int out_size, void* d_ws, size_t ws_size,
                              hipStream_t stream)
{
    (void)n_in; (void)out_size;
    const float* x          = (const float*)d_in[0];
    const float* qkv_w      = (const float*)d_in[1];
    const float* proj_w     = (const float*)d_in[2];
    const float* proj_b     = (const float*)d_in[3];
    const float* bias_table = (const float*)d_in[4];
    const int*   rel        = (const int*)d_in[5];
    const int n_bias = in_sizes[4] / HEADS;

    const size_t qk_elems  = (size_t)BATCH * 2 * HEADS * NTOK * DHEAD;  // 48,168,960
    const size_t v_elems   = (size_t)BATCH * HEADS * DHEAD * 256;       // 25,165,824
    const size_t o_elems   = (size_t)BATCH * HEADS * NTOK * DHEAD;      // 24,084,480
    const size_t bt_elems  = (size_t)HEADS * 256 * 256;                 //    786,432
    uint16_t* qk_ws  = (uint16_t*)d_ws;
    uint16_t* v_ws   = qk_ws + qk_elems;
    uint16_t* o_ws   = v_ws + v_elems;
    uint16_t* bt_ws  = o_ws + o_elems;
    if (ws_size < (qk_elems + v_elems + o_elems + bt_elems) * sizeof(uint16_t)) return;

    bias_pre<<<dim3(HEADS, 256), 256, 0, stream>>>(bias_table, rel, n_bias, bt_ws);

    dim3 g1(2304 / 128, 31360 / 128);
    qkv_gemm_mfma<<<g1, 256, 0, stream>>>(x, qkv_w, qk_ws, v_ws);

    attn_mfma<<<dim3(BATCH * HEADS), 512, 0, stream>>>(qk_ws, v_ws, bt_ws, o_ws);

    dim3 g3(768 / 128, 31360 / 128);
    proj_gemm_mfma<<<g3, 256, 0, stream>>>(o_ws, proj_w, proj_b, (float*)d_out);
}

// Round 4
// 466.201 us; speedup vs baseline: 5.9740x; 1.2094x over previous
//
#include <hip/hip_runtime.h>
#include <hip/hip_bf16.h>
#include <stdint.h>

#define BATCH 128
#define NTOK 245
#define HEADS 12
#define DHEAD 64
#define CDIM 768

typedef __attribute__((ext_vector_type(8))) short short8;
typedef __attribute__((ext_vector_type(4))) float f32x4;

__device__ __forceinline__ float bf2f(uint32_t hbits) {
    union { uint32_t u; float f; } v; v.u = hbits << 16; return v.f;
}
__device__ __forceinline__ uint32_t f2bf(float f) {
    union { float f; uint32_t u; } v; v.f = f;
    return (v.u + 0x7fffu + ((v.u >> 16) & 1u)) >> 16;
}
__device__ __forceinline__ ushort2 pk2bf(float x, float y) {
    union { __hip_bfloat162 h; ushort2 u; } c;
    c.h = __float22bfloat162_rn(make_float2(x, y));
    return c.u;
}

// =============== Kernel A: fp32 -> bf16 bulk convert (8 elems/thread/iter) ==
__global__ __launch_bounds__(256)
void cvt_f32_bf16(const float* __restrict__ src, uint16_t* __restrict__ dst, int n8)
{
    int i = blockIdx.x * 256 + threadIdx.x;
    const int stride = gridDim.x * 256;
    for (; i < n8; i += stride) {
        float4 a = *(const float4*)(src + (size_t)i * 8);
        float4 b = *(const float4*)(src + (size_t)i * 8 + 4);
        ushort2 p0 = pk2bf(a.x, a.y), p1 = pk2bf(a.z, a.w);
        ushort2 p2 = pk2bf(b.x, b.y), p3 = pk2bf(b.z, b.w);
        uint4 o;
        o.x = (uint32_t)p0.x | ((uint32_t)p0.y << 16);
        o.y = (uint32_t)p1.x | ((uint32_t)p1.y << 16);
        o.z = (uint32_t)p2.x | ((uint32_t)p2.y << 16);
        o.w = (uint32_t)p3.x | ((uint32_t)p3.y << 16);
        *(uint4*)(dst + (size_t)i * 8) = o;
    }
}

// =============== Kernel 0: bias precompute =================================
__global__ __launch_bounds__(256)
void bias_pre(const float* __restrict__ bias_table, const int* __restrict__ rel,
              int n_bias, uint16_t* __restrict__ bias_t)
{
    const int h = blockIdx.x, j = blockIdx.y, q = threadIdx.x;
    float v = -30000.f;
    if (j < NTOK && q < NTOK) v = bias_table[(size_t)h * n_bias + rel[q * NTOK + j]];
    bias_t[((size_t)h * 256 + j) * 256 + q] = (uint16_t)f2bf(v);
}

// =============== Kernel 1: QKV projection, bf16 MFMA =======================
// A = x (bf16, pre-converted), B = qkv_w (bf16 if WBF16 else fp32).
// grid: 4410 linear blocks, chunked-XCD swizzled (q=551, r=2).
template<bool WBF16>
__global__ __launch_bounds__(256)
void qkv_gemm_mfma(const uint16_t* __restrict__ xb, const void* __restrict__ Bw_,
                   uint16_t* __restrict__ qk_ws, uint16_t* __restrict__ v_ws)
{
    __shared__ ushort As[128][40];
    __shared__ ushort Bs[128][40];
    const int t = threadIdx.x;
    const int w = t >> 6, l = t & 63;
    const int wr = w >> 1, wc = w & 1;
    const int lm = l & 15, lk = l >> 4;

    const int bid = blockIdx.x;
    const int xcd = bid & 7;
    const int wg = (xcd < 2 ? xcd * 552 : 1104 + (xcd - 2) * 551) + (bid >> 3);
    const int mtile = wg / 18, ctile = wg - mtile * 18;
    const int m0 = mtile * 128, c0 = ctile * 128;

    // bf16 staging coords: each thread 16 contiguous bf16 of one row
    const int sa_r = t >> 1;
    const int sa_c = (t & 1) * 16;
    const uint16_t* aptr = xb + (size_t)(m0 + sa_r) * CDIM + sa_c;
    // fp32 B staging coords (fallback)
    const int sf_r = t >> 3, sf_c = (t & 7) * 4;

    const uint16_t* bptr16 = nullptr;
    const float*    bptr32 = nullptr;
    if constexpr (WBF16) bptr16 = (const uint16_t*)Bw_ + (size_t)(c0 + sa_r) * CDIM + sa_c;
    else                 bptr32 = (const float*)Bw_ + (size_t)(c0 + sf_r) * CDIM + sf_c;
    const size_t rstep32 = (size_t)32 * CDIM;

    f32x4 acc[4][4];
    #pragma unroll
    for (int m = 0; m < 4; ++m)
        #pragma unroll
        for (int n = 0; n < 4; ++n) acc[m][n] = (f32x4){0.f,0.f,0.f,0.f};

    uint4 pa0, pa1, pb0, pb1;
    float4 rb[4];
    pa0 = *(const uint4*)(aptr);
    pa1 = *(const uint4*)(aptr + 8);
    if constexpr (WBF16) {
        pb0 = *(const uint4*)(bptr16);
        pb1 = *(const uint4*)(bptr16 + 8);
    } else {
        #pragma unroll
        for (int i = 0; i < 4; ++i) rb[i] = *(const float4*)(bptr32 + i * rstep32);
    }

    for (int kt = 0; kt < CDIM / 32; ++kt) {
        *(uint4*)&As[sa_r][sa_c]     = pa0;
        *(uint4*)&As[sa_r][sa_c + 8] = pa1;
        if constexpr (WBF16) {
            *(uint4*)&Bs[sa_r][sa_c]     = pb0;
            *(uint4*)&Bs[sa_r][sa_c + 8] = pb1;
        } else {
            #pragma unroll
            for (int i = 0; i < 4; ++i) {
                ushort4 pb;
                ushort2 q0 = pk2bf(rb[i].x, rb[i].y), q1 = pk2bf(rb[i].z, rb[i].w);
                pb.x = q0.x; pb.y = q0.y; pb.z = q1.x; pb.w = q1.y;
                *(ushort4*)&Bs[sf_r + i*32][sf_c] = pb;
            }
        }
        __syncthreads();
        if (kt < CDIM / 32 - 1) {
            const int ko = (kt + 1) * 32;
            pa0 = *(const uint4*)(aptr + ko);
            pa1 = *(const uint4*)(aptr + ko + 8);
            if constexpr (WBF16) {
                pb0 = *(const uint4*)(bptr16 + ko);
                pb1 = *(const uint4*)(bptr16 + ko + 8);
            } else {
                #pragma unroll
                for (int i = 0; i < 4; ++i) rb[i] = *(const float4*)(bptr32 + ko + i * rstep32);
            }
        }
        short8 af[4], bf[4];
        #pragma unroll
        for (int m = 0; m < 4; ++m)
            af[m] = *(const short8*)&As[wr*64 + m*16 + lm][lk * 8];
        #pragma unroll
        for (int n = 0; n < 4; ++n)
            bf[n] = *(const short8*)&Bs[wc*64 + n*16 + lm][lk * 8];
        #pragma unroll
        for (int m = 0; m < 4; ++m)
            #pragma unroll
            for (int n = 0; n < 4; ++n)
                acc[m][n] = __builtin_amdgcn_mfma_f32_16x16x32_bf16(af[m], bf[n], acc[m][n], 0, 0, 0);
        __syncthreads();
    }

    int sarr[4], harr[4], darr[4];
    #pragma unroll
    for (int n = 0; n < 4; ++n) {
        int c = c0 + wc*64 + n*16 + lm;
        int s = c / CDIM; int rem = c - s * CDIM;
        sarr[n] = s; harr[n] = rem >> 6; darr[n] = rem & 63;
    }
    #pragma unroll
    for (int m = 0; m < 4; ++m) {
        #pragma unroll
        for (int r = 0; r < 4; ++r) {
            int gm  = m0 + wr*64 + m*16 + lk*4 + r;
            int b   = gm / NTOK;
            int tok = gm - b * NTOK;
            #pragma unroll
            for (int n = 0; n < 4; ++n) {
                uint16_t val = (uint16_t)f2bf(acc[m][n][r]);
                if (sarr[n] == 2) {
                    v_ws[(((size_t)b*HEADS + harr[n])*DHEAD + darr[n])*256 + tok] = val;
                } else {
                    qk_ws[((((size_t)b*2 + sarr[n])*HEADS + harr[n])*NTOK + tok)*DHEAD + darr[n]] = val;
                }
            }
        }
    }
}

// =============== Kernel 2: MFMA flash attention per (b,h) ==================
__global__ __launch_bounds__(512)
void attn_mfma(const uint16_t* __restrict__ qk, const uint16_t* __restrict__ vt,
               const uint16_t* __restrict__ bias_t, uint16_t* __restrict__ ows)
{
    __shared__ ushort Ks[256][72];
    __shared__ ushort Vt[64][264];
    __shared__ ushort Ps[8][16][72];
    const int bh = blockIdx.x;
    const int b = bh / HEADS, h = bh % HEADS;
    const int t = threadIdx.x;
    const int w = t >> 6, l = t & 63;
    const int lm = l & 15, lk = l >> 4;
    const int wq0 = w * 32;

    const uint16_t* qbase = qk + (((size_t)b*2 + 0)*HEADS + h) * (NTOK*DHEAD);
    const uint16_t* kbase = qk + (((size_t)b*2 + 1)*HEADS + h) * (NTOK*DHEAD);
    const uint16_t* vbase = vt + ((size_t)b*HEADS + h) * (DHEAD*256);
    const uint16_t* btab  = bias_t + (size_t)h * 256 * 256;

    {
        const int col = (t & 7) * 8;
        #pragma unroll
        for (int p = 0; p < 4; ++p) {
            int row = p * 64 + (t >> 3);
            uint4 val = make_uint4(0u,0u,0u,0u);
            if (row < NTOK) val = *(const uint4*)(kbase + (size_t)row * DHEAD + col);
            *(uint4*)&Ks[row][col] = val;
        }
    }
    {
        const int col = (t & 15) * 16;
        #pragma unroll
        for (int p = 0; p < 2; ++p) {
            int row = p * 32 + (t >> 4);
            const uint16_t* src = vbase + (size_t)row * 256;
            uint4 v0 = *(const uint4*)(src + col);
            uint4 v1 = *(const uint4*)(src + col + 8);
            if (col == 240) { v0.z &= 0xffffu; v0.w = 0u; v1 = make_uint4(0u,0u,0u,0u); }
            *(uint4*)&Vt[row][col]     = v0;
            *(uint4*)&Vt[row][col + 8] = v1;
        }
    }

    short8 qf[2][2];
    #pragma unroll
    for (int m = 0; m < 2; ++m) {
        int qrow = wq0 + m*16 + lm; if (qrow > NTOK-1) qrow = NTOK-1;
        #pragma unroll
        for (int k2 = 0; k2 < 2; ++k2)
            qf[m][k2] = *(const short8*)(qbase + (size_t)qrow * DHEAD + k2*32 + lk*8);
    }

    f32x4 acc_o[2][4];
    float mrun[2][4], lrun[2][4];
    #pragma unroll
    for (int m = 0; m < 2; ++m) {
        #pragma unroll
        for (int n = 0; n < 4; ++n) acc_o[m][n] = (f32x4){0.f,0.f,0.f,0.f};
        #pragma unroll
        for (int r = 0; r < 4; ++r) { mrun[m][r] = -1e30f; lrun[m][r] = 0.f; }
    }

    __syncthreads();

    for (int jb = 0; jb < 4; ++jb) {
        short8 kf[4][2], vf[4][2];
        #pragma unroll
        for (int n = 0; n < 4; ++n)
            #pragma unroll
            for (int k2 = 0; k2 < 2; ++k2) {
                kf[n][k2] = *(const short8*)&Ks[jb*64 + n*16 + lm][k2*32 + lk*8];
                vf[n][k2] = *(const short8*)&Vt[n*16 + lm][jb*64 + k2*32 + lk*8];
            }

        #pragma unroll
        for (int m = 0; m < 2; ++m) {
            f32x4 sv[4];
            #pragma unroll
            for (int n = 0; n < 4; ++n) {
                f32x4 z = (f32x4){0.f,0.f,0.f,0.f};
                sv[n] = __builtin_amdgcn_mfma_f32_16x16x32_bf16(qf[m][0], kf[n][0], z, 0, 0, 0);
                sv[n] = __builtin_amdgcn_mfma_f32_16x16x32_bf16(qf[m][1], kf[n][1], sv[n], 0, 0, 0);
            }
            #pragma unroll
            for (int n = 0; n < 4; ++n) {
                uint2 bb = *(const uint2*)(btab + (size_t)(jb*64 + n*16 + lm) * 256 + wq0 + m*16 + lk*4);
                sv[n][0] = fmaf(sv[n][0], 0.125f, bf2f(bb.x & 0xffffu));
                sv[n][1] = fmaf(sv[n][1], 0.125f, bf2f(bb.x >> 16));
                sv[n][2] = fmaf(sv[n][2], 0.125f, bf2f(bb.y & 0xffffu));
                sv[n][3] = fmaf(sv[n][3], 0.125f, bf2f(bb.y >> 16));
            }
            float nm[4], corr[4];
            #pragma unroll
            for (int r = 0; r < 4; ++r) {
                float rmax = fmaxf(fmaxf(sv[0][r], sv[1][r]), fmaxf(sv[2][r], sv[3][r]));
                rmax = fmaxf(rmax, __shfl_xor(rmax, 1));
                rmax = fmaxf(rmax, __shfl_xor(rmax, 2));
                rmax = fmaxf(rmax, __shfl_xor(rmax, 4));
                rmax = fmaxf(rmax, __shfl_xor(rmax, 8));
                nm[r] = fmaxf(mrun[m][r], rmax);
                corr[r] = __expf(mrun[m][r] - nm[r]);
                mrun[m][r] = nm[r];
            }
            ushort pu[4][4];
            float rs[4] = {0.f, 0.f, 0.f, 0.f};
            #pragma unroll
            for (int n = 0; n < 4; ++n)
                #pragma unroll
                for (int r = 0; r < 4; ++r) {
                    float p = __expf(sv[n][r] - nm[r]);
                    ushort u = (ushort)f2bf(p);
                    pu[n][r] = u;
                    rs[r] += bf2f(u);
                }
            #pragma unroll
            for (int r = 0; r < 4; ++r) {
                rs[r] += __shfl_xor(rs[r], 1);
                rs[r] += __shfl_xor(rs[r], 2);
                rs[r] += __shfl_xor(rs[r], 4);
                rs[r] += __shfl_xor(rs[r], 8);
                lrun[m][r] = lrun[m][r] * corr[r] + rs[r];
            }
            #pragma unroll
            for (int n = 0; n < 4; ++n)
                #pragma unroll
                for (int r = 0; r < 4; ++r)
                    acc_o[m][n][r] *= corr[r];
            #pragma unroll
            for (int n = 0; n < 4; ++n)
                #pragma unroll
                for (int r = 0; r < 4; ++r)
                    Ps[w][lk*4 + r][n*16 + lm] = pu[n][r];
            short8 pf[2];
            #pragma unroll
            for (int k2 = 0; k2 < 2; ++k2)
                pf[k2] = *(const short8*)&Ps[w][lm][k2*32 + lk*8];
            #pragma unroll
            for (int n = 0; n < 4; ++n) {
                acc_o[m][n] = __builtin_amdgcn_mfma_f32_16x16x32_bf16(pf[0], vf[n][0], acc_o[m][n], 0, 0, 0);
                acc_o[m][n] = __builtin_amdgcn_mfma_f32_16x16x32_bf16(pf[1], vf[n][1], acc_o[m][n], 0, 0, 0);
            }
        }
    }

    uint16_t* obase = ows + ((size_t)b*HEADS + h) * (NTOK*DHEAD);
    #pragma unroll
    for (int m = 0; m < 2; ++m) {
        float inv[4];
        #pragma unroll
        for (int r = 0; r < 4; ++r) inv[r] = 1.f / lrun[m][r];
        #pragma unroll
        for (int r = 0; r < 4; ++r) {
            int q = wq0 + m*16 + lk*4 + r;
            if (q < NTOK) {
                #pragma unroll
                for (int n = 0; n < 4; ++n)
                    obase[(size_t)q * DHEAD + n*16 + lm] = (uint16_t)f2bf(acc_o[m][n][r] * inv[r]);
            }
        }
    }
}

// =============== Kernel 3: output projection, bf16 MFMA ====================
// grid: 1470 linear blocks, chunked-XCD swizzled (q=183, r=6).
template<bool WBF16>
__global__ __launch_bounds__(256)
void proj_gemm_mfma(const uint16_t* __restrict__ ows, const void* __restrict__ Bw_,
                    const float* __restrict__ bias, float* __restrict__ out)
{
    __shared__ ushort As[128][40];
    __shared__ ushort Bs[128][40];
    const int t = threadIdx.x;
    const int w = t >> 6, l = t & 63;
    const int wr = w >> 1, wc = w & 1;
    const int lm = l & 15, lk = l >> 4;

    const int bid = blockIdx.x;
    const int xcd = bid & 7;
    const int wg = (xcd < 6 ? xcd * 184 : 1104 + (xcd - 6) * 183) + (bid >> 3);
    const int mtile = wg / 6, ctile = wg - mtile * 6;
    const int m0 = mtile * 128, c0 = ctile * 128;

    const int sr2 = t >> 2;
    const int sc2 = (t & 3) * 8;
    size_t abase[2];
    #pragma unroll
    for (int i = 0; i < 2; ++i) {
        int gm  = m0 + sr2 + i*64;
        int b   = gm / NTOK;
        int tok = gm - b * NTOK;
        abase[i] = ((size_t)b * HEADS * NTOK + tok) * DHEAD + sc2;
    }
    const int sa_r = t >> 1, sa_c = (t & 1) * 16;
    const int sf_r = t >> 3, sf_c = (t & 7) * 4;
    const uint16_t* bptr16 = nullptr;
    const float*    bptr32 = nullptr;
    if constexpr (WBF16) bptr16 = (const uint16_t*)Bw_ + (size_t)(c0 + sa_r) * CDIM + sa_c;
    else                 bptr32 = (const float*)Bw_ + (size_t)(c0 + sf_r) * CDIM + sf_c;
    const size_t rstep32 = (size_t)32 * CDIM;

    f32x4 acc[4][4];
    #pragma unroll
    for (int m = 0; m < 4; ++m)
        #pragma unroll
        for (int n = 0; n < 4; ++n) acc[m][n] = (f32x4){0.f,0.f,0.f,0.f};

    uint4  pa[2], pb0, pb1;
    float4 rb[4];
    #pragma unroll
    for (int i = 0; i < 2; ++i)
        pa[i] = *(const uint4*)(ows + abase[i]);
    if constexpr (WBF16) {
        pb0 = *(const uint4*)(bptr16);
        pb1 = *(const uint4*)(bptr16 + 8);
    } else {
        #pragma unroll
        for (int i = 0; i < 4; ++i) rb[i] = *(const float4*)(bptr32 + i * rstep32);
    }

    for (int kt = 0; kt < CDIM / 32; ++kt) {
        #pragma unroll
        for (int i = 0; i < 2; ++i)
            *(uint4*)&As[sr2 + i*64][sc2] = pa[i];
        if constexpr (WBF16) {
            *(uint4*)&Bs[sa_r][sa_c]     = pb0;
            *(uint4*)&Bs[sa_r][sa_c + 8] = pb1;
        } else {
            #pragma unroll
            for (int i = 0; i < 4; ++i) {
                ushort4 pkv;
                ushort2 q0 = pk2bf(rb[i].x, rb[i].y), q1 = pk2bf(rb[i].z, rb[i].w);
                pkv.x = q0.x; pkv.y = q0.y; pkv.z = q1.x; pkv.w = q1.y;
                *(ushort4*)&Bs[sf_r + i*32][sf_c] = pkv;
            }
        }
        __syncthreads();
        if (kt < CDIM / 32 - 1) {
            const int kn = kt + 1;
            const size_t aoff = (size_t)(kn >> 1) * NTOK * DHEAD + (kn & 1) * 32;
            #pragma unroll
            for (int i = 0; i < 2; ++i)
                pa[i] = *(const uint4*)(ows + abase[i] + aoff);
            if constexpr (WBF16) {
                pb0 = *(const uint4*)(bptr16 + kn * 32);
                pb1 = *(const uint4*)(bptr16 + kn * 32 + 8);
            } else {
                #pragma unroll
                for (int i = 0; i < 4; ++i) rb[i] = *(const float4*)(bptr32 + kn * 32 + i * rstep32);
            }
        }
        short8 af[4], bf[4];
        #pragma unroll
        for (int m = 0; m < 4; ++m)
            af[m] = *(const short8*)&As[wr*64 + m*16 + lm][lk * 8];
        #pragma unroll
        for (int n = 0; n < 4; ++n)
            bf[n] = *(const short8*)&Bs[wc*64 + n*16 + lm][lk * 8];
        #pragma unroll
        for (int m = 0; m < 4; ++m)
            #pragma unroll
            for (int n = 0; n < 4; ++n)
                acc[m][n] = __builtin_amdgcn_mfma_f32_16x16x32_bf16(af[m], bf[n], acc[m][n], 0, 0, 0);
        __syncthreads();
    }

    float bs[4]; int carr[4];
    #pragma unroll
    for (int n = 0; n < 4; ++n) {
        carr[n] = c0 + wc*64 + n*16 + lm;
        bs[n]   = bias[carr[n]];
    }
    #pragma unroll
    for (int m = 0; m < 4; ++m) {
        #pragma unroll
        for (int r = 0; r < 4; ++r) {
            int gm = m0 + wr*64 + m*16 + lk*4 + r;
            #pragma unroll
            for (int n = 0; n < 4; ++n)
                out[(size_t)gm * CDIM + carr[n]] = acc[m][n][r] + bs[n];
        }
    }
}

extern "C" void kernel_launch(void* const* d_in, const int* in_sizes, int n_in,
                              void* d_out, int out_size, void* d_ws, size_t ws_size,
                              hipStream_t stream)
{
    (void)n_in; (void)out_size;
    const float* x          = (const float*)d_in[0];
    const float* qkv_w      = (const float*)d_in[1];
    const float* proj_w     = (const float*)d_in[2];
    const float* proj_b     = (const float*)d_in[3];
    const float* bias_table = (const float*)d_in[4];
    const int*   rel        = (const int*)d_in[5];
    const int n_bias = in_sizes[4] / HEADS;

    const size_t qk_elems = (size_t)BATCH * 2 * HEADS * NTOK * DHEAD;  // 48,168,960
    const size_t v_elems  = (size_t)BATCH * HEADS * DHEAD * 256;       // 25,165,824
    const size_t o_elems  = (size_t)BATCH * HEADS * NTOK * DHEAD;      // 24,084,480 (= x elems)
    const size_t bt_elems = (size_t)HEADS * 256 * 256;                 //    786,432
    const size_t wq_elems = (size_t)3 * CDIM * CDIM;                   //  1,769,472
    const size_t wp_elems = (size_t)CDIM * CDIM;                       //    589,824

    uint16_t* qk_ws = (uint16_t*)d_ws;
    uint16_t* v_ws  = qk_ws + qk_elems;
    uint16_t* o_ws  = v_ws + v_elems;       // doubles as x_bf16 before attn runs
    uint16_t* bt_ws = o_ws + o_elems;
    uint16_t* wq_ws = bt_ws + bt_elems;
    uint16_t* wp_ws = wq_ws + wq_elems;

    const size_t base_need = (qk_elems + v_elems + o_elems + bt_elems) * sizeof(uint16_t);
    const size_t full_need = base_need + (wq_elems + wp_elems) * sizeof(uint16_t);
    if (ws_size < base_need) return;
    const bool wbf = ws_size >= full_need;

    uint16_t* xb = o_ws;   // alias: x_bf16 lives in O region until attn overwrites it

    // x -> bf16 (always; 3,010,560 groups of 8)
    cvt_f32_bf16<<<2048, 256, 0, stream>>>(x, xb, (int)(o_elems / 8));
    if (wbf) {
        cvt_f32_bf16<<<864, 256, 0, stream>>>(qkv_w, wq_ws, (int)(wq_elems / 8));
        cvt_f32_bf16<<<288, 256, 0, stream>>>(proj_w, wp_ws, (int)(wp_elems / 8));
    }

    bias_pre<<<dim3(HEADS, 256), 256, 0, stream>>>(bias_table, rel, n_bias, bt_ws);

    if (wbf) qkv_gemm_mfma<true ><<<4410, 256, 0, stream>>>(xb, wq_ws, qk_ws, v_ws);
    else     qkv_gemm_mfma<false><<<4410, 256, 0, stream>>>(xb, qkv_w, qk_ws, v_ws);

    attn_mfma<<<dim3(BATCH * HEADS), 512, 0, stream>>>(qk_ws, v_ws, bt_ws, o_ws);

    if (wbf) proj_gemm_mfma<true ><<<1470, 256, 0, stream>>>(o_ws, wp_ws, proj_b, (float*)d_out);
    else     proj_gemm_mfma<false><<<1470, 256, 0, stream>>>(o_ws, proj_w, proj_b, (float*)d_out);
}

// Round 6
// 443.809 us; speedup vs baseline: 6.2755x; 1.0505x over previous
//
#include <hip/hip_runtime.h>
#include <hip/hip_bf16.h>
#include <stdint.h>

#define BATCH 128
#define NTOK 245
#define HEADS 12
#define DHEAD 64
#define CDIM 768

typedef __attribute__((ext_vector_type(8))) short short8;
typedef __attribute__((ext_vector_type(4))) float f32x4;

__device__ __forceinline__ float bf2f(uint32_t hbits) {
    union { uint32_t u; float f; } v; v.u = hbits << 16; return v.f;
}
__device__ __forceinline__ uint32_t f2bf(float f) {
    union { float f; uint32_t u; } v; v.f = f;
    return (v.u + 0x7fffu + ((v.u >> 16) & 1u)) >> 16;
}
__device__ __forceinline__ ushort2 pk2bf(float x, float y) {
    union { __hip_bfloat162 h; ushort2 u; } c;
    c.h = __float22bfloat162_rn(make_float2(x, y));
    return c.u;
}

// =============== Kernel A: fp32 -> bf16 bulk convert ========================
__global__ __launch_bounds__(256)
void cvt_f32_bf16(const float* __restrict__ src, uint16_t* __restrict__ dst, int n8)
{
    int i = blockIdx.x * 256 + threadIdx.x;
    const int stride = gridDim.x * 256;
    for (; i < n8; i += stride) {
        float4 a = *(const float4*)(src + (size_t)i * 8);
        float4 b = *(const float4*)(src + (size_t)i * 8 + 4);
        ushort2 p0 = pk2bf(a.x, a.y), p1 = pk2bf(a.z, a.w);
        ushort2 p2 = pk2bf(b.x, b.y), p3 = pk2bf(b.z, b.w);
        uint4 o;
        o.x = (uint32_t)p0.x | ((uint32_t)p0.y << 16);
        o.y = (uint32_t)p1.x | ((uint32_t)p1.y << 16);
        o.z = (uint32_t)p2.x | ((uint32_t)p2.y << 16);
        o.w = (uint32_t)p3.x | ((uint32_t)p3.y << 16);
        *(uint4*)(dst + (size_t)i * 8) = o;
    }
}

// =============== Kernel 0: bias precompute =================================
__global__ __launch_bounds__(256)
void bias_pre(const float* __restrict__ bias_table, const int* __restrict__ rel,
              int n_bias, uint16_t* __restrict__ bias_t)
{
    const int h = blockIdx.x, j = blockIdx.y, q = threadIdx.x;
    float v = -30000.f;
    if (j < NTOK && q < NTOK) v = bias_table[(size_t)h * n_bias + rel[q * NTOK + j]];
    bias_t[((size_t)h * 256 + j) * 256 + q] = (uint16_t)f2bf(v);
}

// =============== Kernel 1: QKV projection, bf16 MFMA =======================
// LDS in MFMA-fragment order: frag reads are lane-contiguous (0 conflicts).
// Operands swapped in mfma -> lane holds 4 consecutive c -> packed stores.
// Fragment slot for element [row][k]: Af[row>>4][(row&15) + 16*((k&31)>>3)][k&7].
// Slot stride per k-group = 16 lanes * 8 ushorts = 128 ushorts.
__global__ __launch_bounds__(256)
void qkv_gemm_mfma(const uint16_t* __restrict__ xb, const uint16_t* __restrict__ wq,
                   uint16_t* __restrict__ qkv)
{
    __shared__ ushort Af[8][64][8];   // 8 KB
    __shared__ ushort Bf[8][64][8];   // 8 KB
    const int t = threadIdx.x;
    const int w = t >> 6, l = t & 63;
    const int wr = w >> 1, wc = w & 1;
    const int lm = l & 15, lk = l >> 4;

    const int bid = blockIdx.x;
    const int xcd = bid & 7;
    const int wg = (xcd < 2 ? xcd * 552 : 1104 + (xcd - 2) * 551) + (bid >> 3);
    const int mtile = wg / 18, ctile = wg - mtile * 18;
    const int m0 = mtile * 128, c0 = ctile * 128;

    // staging: row = t>>1 (0..127), khalf = t&1 selects k 0..15 or 16..31
    const int srow = t >> 1;
    const int khalf = t & 1;
    const uint16_t* aptr = xb + (size_t)(m0 + srow) * CDIM + khalf * 16;
    const uint16_t* bptr = wq + (size_t)(c0 + srow) * CDIM + khalf * 16;
    // k-groups 2*khalf (elems k%32 in [16*khalf,16*khalf+8)) and 2*khalf+1
    ushort* adst0 = &Af[srow >> 4][(srow & 15) + 16 * (2 * khalf)][0];
    ushort* bdst0 = &Bf[srow >> 4][(srow & 15) + 16 * (2 * khalf)][0];

    f32x4 acc[4][4];
    #pragma unroll
    for (int m = 0; m < 4; ++m)
        #pragma unroll
        for (int n = 0; n < 4; ++n) acc[m][n] = (f32x4){0.f,0.f,0.f,0.f};

    uint4 pa0, pa1, pb0, pb1;
    pa0 = *(const uint4*)(aptr);
    pa1 = *(const uint4*)(aptr + 8);
    pb0 = *(const uint4*)(bptr);
    pb1 = *(const uint4*)(bptr + 8);

    for (int kt = 0; kt < CDIM / 32; ++kt) {
        *(uint4*)(adst0)       = pa0;
        *(uint4*)(adst0 + 128) = pa1;    // next k-group: +16 lanes * 8 ushorts
        *(uint4*)(bdst0)       = pb0;
        *(uint4*)(bdst0 + 128) = pb1;
        __syncthreads();
        if (kt < CDIM / 32 - 1) {
            const int ko = (kt + 1) * 32;
            pa0 = *(const uint4*)(aptr + ko);
            pa1 = *(const uint4*)(aptr + ko + 8);
            pb0 = *(const uint4*)(bptr + ko);
            pb1 = *(const uint4*)(bptr + ko + 8);
        }
        short8 af[4], bf[4];
        #pragma unroll
        for (int m = 0; m < 4; ++m)
            af[m] = *(const short8*)&Af[wr*4 + m][l][0];
        #pragma unroll
        for (int n = 0; n < 4; ++n)
            bf[n] = *(const short8*)&Bf[wc*4 + n][l][0];
        #pragma unroll
        for (int m = 0; m < 4; ++m)
            #pragma unroll
            for (int n = 0; n < 4; ++n)   // swapped: A=weights, B=tokens
                acc[m][n] = __builtin_amdgcn_mfma_f32_16x16x32_bf16(bf[n], af[m], acc[m][n], 0, 0, 0);
        __syncthreads();
    }

    // epilogue: lane lm = token, regs = 4 consecutive c (lk*4 + r)
    int sArr[4], hArr[4], dArr[4];
    #pragma unroll
    for (int n = 0; n < 4; ++n) {
        int c = c0 + wc*64 + n*16 + lk*4;
        int s = c / CDIM; int rem = c - s * CDIM;
        sArr[n] = s; hArr[n] = rem >> 6; dArr[n] = rem & 63;
    }
    #pragma unroll
    for (int m = 0; m < 4; ++m) {
        int gm  = m0 + wr*64 + m*16 + lm;
        int b   = gm / NTOK;
        int tok = gm - b * NTOK;
        #pragma unroll
        for (int n = 0; n < 4; ++n) {
            ushort2 u0 = pk2bf(acc[m][n][0], acc[m][n][1]);
            ushort2 u1 = pk2bf(acc[m][n][2], acc[m][n][3]);
            uint2 pk;
            pk.x = (uint32_t)u0.x | ((uint32_t)u0.y << 16);
            pk.y = (uint32_t)u1.x | ((uint32_t)u1.y << 16);
            size_t addr = ((((size_t)b*3 + sArr[n])*HEADS + hArr[n])*NTOK + tok)*DHEAD + dArr[n];
            *(uint2*)(qkv + addr) = pk;
        }
    }
}

// =============== Kernel 2: MFMA flash attention per (b,h) ==================
__global__ __launch_bounds__(512)
void attn_mfma(const uint16_t* __restrict__ qkv, const uint16_t* __restrict__ bias_t,
               uint16_t* __restrict__ ows)
{
    __shared__ ushort Ks[256][72];
    __shared__ ushort Vt[64][264];
    __shared__ ushort Ps[8][16][72];
    const int bh = blockIdx.x;
    const int b = bh / HEADS, h = bh % HEADS;
    const int t = threadIdx.x;
    const int w = t >> 6, l = t & 63;
    const int lm = l & 15, lk = l >> 4;
    const int wq0 = w * 32;

    const uint16_t* qbase = qkv + (((size_t)b*3 + 0)*HEADS + h) * (NTOK*DHEAD);
    const uint16_t* kbase = qkv + (((size_t)b*3 + 1)*HEADS + h) * (NTOK*DHEAD);
    const uint16_t* vbase = qkv + (((size_t)b*3 + 2)*HEADS + h) * (NTOK*DHEAD);
    const uint16_t* btab  = bias_t + (size_t)h * 256 * 256;

    // ---- stage K (rows >= 245 zeroed) ----
    {
        const int col = (t & 7) * 8;
        #pragma unroll
        for (int p = 0; p < 4; ++p) {
            int row = p * 64 + (t >> 3);
            uint4 val = make_uint4(0u,0u,0u,0u);
            if (row < NTOK) val = *(const uint4*)(kbase + (size_t)row * DHEAD + col);
            *(uint4*)&Ks[row][col] = val;
        }
    }
    // ---- stage V row-major -> transposed Vt[d][j] (one-time) ----
    {
        const int j  = t >> 1;          // 0..255
        const int dh = (t & 1) * 32;
        uint4 r0 = make_uint4(0,0,0,0), r1 = r0, r2 = r0, r3 = r0;
        if (j < NTOK) {
            const uint16_t* src = vbase + (size_t)j * DHEAD + dh;
            r0 = *(const uint4*)(src);
            r1 = *(const uint4*)(src + 8);
            r2 = *(const uint4*)(src + 16);
            r3 = *(const uint4*)(src + 24);
        }
        union { uint4 v[4]; ushort s[32]; } u;
        u.v[0] = r0; u.v[1] = r1; u.v[2] = r2; u.v[3] = r3;
        #pragma unroll
        for (int i = 0; i < 32; ++i)
            Vt[dh + i][j] = u.s[i];
    }

    short8 qf[2][2];
    #pragma unroll
    for (int m = 0; m < 2; ++m) {
        int qrow = wq0 + m*16 + lm; if (qrow > NTOK-1) qrow = NTOK-1;
        #pragma unroll
        for (int k2 = 0; k2 < 2; ++k2)
            qf[m][k2] = *(const short8*)(qbase + (size_t)qrow * DHEAD + k2*32 + lk*8);
    }

    f32x4 acc_o[2][4];
    float mrun[2][4], lrun[2][4];
    #pragma unroll
    for (int m = 0; m < 2; ++m) {
        #pragma unroll
        for (int n = 0; n < 4; ++n) acc_o[m][n] = (f32x4){0.f,0.f,0.f,0.f};
        #pragma unroll
        for (int r = 0; r < 4; ++r) { mrun[m][r] = -1e30f; lrun[m][r] = 0.f; }
    }

    __syncthreads();

    for (int jb = 0; jb < 4; ++jb) {
        short8 kf[4][2], vf[4][2];
        #pragma unroll
        for (int n = 0; n < 4; ++n)
            #pragma unroll
            for (int k2 = 0; k2 < 2; ++k2) {
                kf[n][k2] = *(const short8*)&Ks[jb*64 + n*16 + lm][k2*32 + lk*8];
                vf[n][k2] = *(const short8*)&Vt[n*16 + lm][jb*64 + k2*32 + lk*8];
            }

        #pragma unroll
        for (int m = 0; m < 2; ++m) {
            f32x4 sv[4];
            #pragma unroll
            for (int n = 0; n < 4; ++n) {
                f32x4 z = (f32x4){0.f,0.f,0.f,0.f};
                sv[n] = __builtin_amdgcn_mfma_f32_16x16x32_bf16(qf[m][0], kf[n][0], z, 0, 0, 0);
                sv[n] = __builtin_amdgcn_mfma_f32_16x16x32_bf16(qf[m][1], kf[n][1], sv[n], 0, 0, 0);
            }
            #pragma unroll
            for (int n = 0; n < 4; ++n) {
                uint2 bb = *(const uint2*)(btab + (size_t)(jb*64 + n*16 + lm) * 256 + wq0 + m*16 + lk*4);
                sv[n][0] = fmaf(sv[n][0], 0.125f, bf2f(bb.x & 0xffffu));
                sv[n][1] = fmaf(sv[n][1], 0.125f, bf2f(bb.x >> 16));
                sv[n][2] = fmaf(sv[n][2], 0.125f, bf2f(bb.y & 0xffffu));
                sv[n][3] = fmaf(sv[n][3], 0.125f, bf2f(bb.y >> 16));
            }
            float nm[4], corr[4];
            #pragma unroll
            for (int r = 0; r < 4; ++r) {
                float rmax = fmaxf(fmaxf(sv[0][r], sv[1][r]), fmaxf(sv[2][r], sv[3][r]));
                rmax = fmaxf(rmax, __shfl_xor(rmax, 1));
                rmax = fmaxf(rmax, __shfl_xor(rmax, 2));
                rmax = fmaxf(rmax, __shfl_xor(rmax, 4));
                rmax = fmaxf(rmax, __shfl_xor(rmax, 8));
                nm[r] = fmaxf(mrun[m][r], rmax);
                corr[r] = __expf(mrun[m][r] - nm[r]);
                mrun[m][r] = nm[r];
            }
            ushort pu[4][4];
            float rs[4] = {0.f, 0.f, 0.f, 0.f};
            #pragma unroll
            for (int n = 0; n < 4; ++n)
                #pragma unroll
                for (int r = 0; r < 4; ++r) {
                    float p = __expf(sv[n][r] - nm[r]);
                    ushort u = (ushort)f2bf(p);
                    pu[n][r] = u;
                    rs[r] += bf2f(u);
                }
            #pragma unroll
            for (int r = 0; r < 4; ++r) {
                rs[r] += __shfl_xor(rs[r], 1);
                rs[r] += __shfl_xor(rs[r], 2);
                rs[r] += __shfl_xor(rs[r], 4);
                rs[r] += __shfl_xor(rs[r], 8);
                lrun[m][r] = lrun[m][r] * corr[r] + rs[r];
            }
            #pragma unroll
            for (int n = 0; n < 4; ++n)
                #pragma unroll
                for (int r = 0; r < 4; ++r)
                    acc_o[m][n][r] *= corr[r];
            #pragma unroll
            for (int n = 0; n < 4; ++n)
                #pragma unroll
                for (int r = 0; r < 4; ++r)
                    Ps[w][lk*4 + r][n*16 + lm] = pu[n][r];
            short8 pf[2];
            #pragma unroll
            for (int k2 = 0; k2 < 2; ++k2)
                pf[k2] = *(const short8*)&Ps[w][lm][k2*32 + lk*8];
            #pragma unroll
            for (int n = 0; n < 4; ++n) {
                acc_o[m][n] = __builtin_amdgcn_mfma_f32_16x16x32_bf16(pf[0], vf[n][0], acc_o[m][n], 0, 0, 0);
                acc_o[m][n] = __builtin_amdgcn_mfma_f32_16x16x32_bf16(pf[1], vf[n][1], acc_o[m][n], 0, 0, 0);
            }
        }
    }

    uint16_t* obase = ows + ((size_t)b*HEADS + h) * (NTOK*DHEAD);
    #pragma unroll
    for (int m = 0; m < 2; ++m) {
        float inv[4];
        #pragma unroll
        for (int r = 0; r < 4; ++r) inv[r] = 1.f / lrun[m][r];
        #pragma unroll
        for (int r = 0; r < 4; ++r) {
            int q = wq0 + m*16 + lk*4 + r;
            if (q < NTOK) {
                #pragma unroll
                for (int n = 0; n < 4; ++n)
                    obase[(size_t)q * DHEAD + n*16 + lm] = (uint16_t)f2bf(acc_o[m][n][r] * inv[r]);
            }
        }
    }
}

// =============== Kernel 3: output projection, bf16 MFMA ====================
__global__ __launch_bounds__(256)
void proj_gemm_mfma(const uint16_t* __restrict__ ows, const uint16_t* __restrict__ wp,
                    const float* __restrict__ bias, float* __restrict__ out)
{
    __shared__ ushort Af[8][64][8];
    __shared__ ushort Bf[8][64][8];
    const int t = threadIdx.x;
    const int w = t >> 6, l = t & 63;
    const int wr = w >> 1, wc = w & 1;
    const int lm = l & 15, lk = l >> 4;

    const int bid = blockIdx.x;
    const int xcd = bid & 7;
    const int wg = (xcd < 6 ? xcd * 184 : 1104 + (xcd - 6) * 183) + (bid >> 3);
    const int mtile = wg / 6, ctile = wg - mtile * 6;
    const int m0 = mtile * 128, c0 = ctile * 128;

    // A staging: thread covers rows {sr2, sr2+64}, one 8-bf16 slot each
    const int sr2 = t >> 2;
    const int kg  = t & 3;               // k-group within 32-k tile
    size_t abase[2];
    ushort* adst[2];
    #pragma unroll
    for (int i = 0; i < 2; ++i) {
        int row = sr2 + i*64;
        int gm  = m0 + row;
        int b   = gm / NTOK;
        int tok = gm - b * NTOK;
        abase[i] = ((size_t)b * HEADS * NTOK + tok) * DHEAD + kg * 8;
        adst[i]  = &Af[row >> 4][(row & 15) + 16 * kg][0];
    }
    // B staging
    const int srow = t >> 1;
    const int khalf = t & 1;
    const uint16_t* bptr = wp + (size_t)(c0 + srow) * CDIM + khalf * 16;
    ushort* bdst0 = &Bf[srow >> 4][(srow & 15) + 16 * (2 * khalf)][0];

    f32x4 acc[4][4];
    #pragma unroll
    for (int m = 0; m < 4; ++m)
        #pragma unroll
        for (int n = 0; n < 4; ++n) acc[m][n] = (f32x4){0.f,0.f,0.f,0.f};

    uint4 pa[2], pb0, pb1;
    #pragma unroll
    for (int i = 0; i < 2; ++i)
        pa[i] = *(const uint4*)(ows + abase[i]);
    pb0 = *(const uint4*)(bptr);
    pb1 = *(const uint4*)(bptr + 8);

    for (int kt = 0; kt < CDIM / 32; ++kt) {
        #pragma unroll
        for (int i = 0; i < 2; ++i)
            *(uint4*)(adst[i]) = pa[i];
        *(uint4*)(bdst0)       = pb0;
        *(uint4*)(bdst0 + 128) = pb1;    // +16 lanes * 8 ushorts
        __syncthreads();
        if (kt < CDIM / 32 - 1) {
            const int kn = kt + 1;
            const size_t aoff = (size_t)(kn >> 1) * NTOK * DHEAD + (kn & 1) * 32;
            #pragma unroll
            for (int i = 0; i < 2; ++i)
                pa[i] = *(const uint4*)(ows + abase[i] + aoff);
            pb0 = *(const uint4*)(bptr + kn * 32);
            pb1 = *(const uint4*)(bptr + kn * 32 + 8);
        }
        short8 af[4], bf[4];
        #pragma unroll
        for (int m = 0; m < 4; ++m)
            af[m] = *(const short8*)&Af[wr*4 + m][l][0];
        #pragma unroll
        for (int n = 0; n < 4; ++n)
            bf[n] = *(const short8*)&Bf[wc*4 + n][l][0];
        #pragma unroll
        for (int m = 0; m < 4; ++m)
            #pragma unroll
            for (int n = 0; n < 4; ++n)
                acc[m][n] = __builtin_amdgcn_mfma_f32_16x16x32_bf16(bf[n], af[m], acc[m][n], 0, 0, 0);
        __syncthreads();
    }

    float4 bsv[4]; int cArr[4];
    #pragma unroll
    for (int n = 0; n < 4; ++n) {
        cArr[n] = c0 + wc*64 + n*16 + lk*4;
        bsv[n]  = *(const float4*)(bias + cArr[n]);
    }
    #pragma unroll
    for (int m = 0; m < 4; ++m) {
        int gm = m0 + wr*64 + m*16 + lm;
        #pragma unroll
        for (int n = 0; n < 4; ++n) {
            float4 r;
            r.x = acc[m][n][0] + bsv[n].x;
            r.y = acc[m][n][1] + bsv[n].y;
            r.z = acc[m][n][2] + bsv[n].z;
            r.w = acc[m][n][3] + bsv[n].w;
            *(float4*)(out + (size_t)gm * CDIM + cArr[n]) = r;
        }
    }
}

extern "C" void kernel_launch(void* const* d_in, const int* in_sizes, int n_in,
                              void* d_out, int out_size, void* d_ws, size_t ws_size,
                              hipStream_t stream)
{
    (void)n_in; (void)out_size;
    const float* x          = (const float*)d_in[0];
    const float* qkv_w      = (const float*)d_in[1];
    const float* proj_w     = (const float*)d_in[2];
    const float* proj_b     = (const float*)d_in[3];
    const float* bias_table = (const float*)d_in[4];
    const int*   rel        = (const int*)d_in[5];
    const int n_bias = in_sizes[4] / HEADS;

    const size_t qkv_elems = (size_t)BATCH * 3 * HEADS * NTOK * DHEAD;  // 72,253,440
    const size_t o_elems   = (size_t)BATCH * HEADS * NTOK * DHEAD;      // 24,084,480 (= x elems)
    const size_t bt_elems  = (size_t)HEADS * 256 * 256;                 //    786,432
    const size_t wq_elems  = (size_t)3 * CDIM * CDIM;                   //  1,769,472
    const size_t wp_elems  = (size_t)CDIM * CDIM;                       //    589,824

    uint16_t* qkv_ws = (uint16_t*)d_ws;
    uint16_t* o_ws   = qkv_ws + qkv_elems;   // doubles as x_bf16 until attn writes it
    uint16_t* bt_ws  = o_ws + o_elems;
    uint16_t* wq_ws  = bt_ws + bt_elems;
    uint16_t* wp_ws  = wq_ws + wq_elems;
    const size_t need = (qkv_elems + o_elems + bt_elems + wq_elems + wp_elems) * sizeof(uint16_t);
    if (ws_size < need) return;   // ~199 MB

    uint16_t* xb = o_ws;

    cvt_f32_bf16<<<2048, 256, 0, stream>>>(x, xb, (int)(o_elems / 8));
    cvt_f32_bf16<<<864, 256, 0, stream>>>(qkv_w, wq_ws, (int)(wq_elems / 8));
    cvt_f32_bf16<<<288, 256, 0, stream>>>(proj_w, wp_ws, (int)(wp_elems / 8));

    bias_pre<<<dim3(HEADS, 256), 256, 0, stream>>>(bias_table, rel, n_bias, bt_ws);

    qkv_gemm_mfma<<<4410, 256, 0, stream>>>(xb, wq_ws, qkv_ws);

    attn_mfma<<<dim3(BATCH * HEADS), 512, 0, stream>>>(qkv_ws, bt_ws, o_ws);

    proj_gemm_mfma<<<1470, 256, 0, stream>>>(o_ws, wp_ws, proj_b, (float*)d_out);
}